// Round 3
// baseline (210.054 us; speedup 1.0000x reference)
//
#include <hip/hip_runtime.h>
#include <climits>

// FirstSpikeDetector: out[b][t] = 1.0 iff t is the first index where
// spike_train[b][t] != 0, else 0.0. (NOT/AND/OR gate cascade over a scan
// collapses to "keep only the first spike per row".)
//
// One wave64 per row (T=2048). Read phase: 2x float4 per lane = 512
// elements/wave/iter, early-exit via __ballot (at ~10% firing rate,
// P(resolve in iter 0) = 1 - 0.9^512 ~= 1, so ~2 KB read per row).
// Write phase: 4 iterations of 2x nontemporal float4 stores of the
// one-hot row (134 MB total, the irreducible cost since d_out is
// re-poisoned before every launch).

typedef float nfloat4 __attribute__((ext_vector_type(4)));  // clang vector: valid for __builtin_nontemporal_store

__global__ __launch_bounds__(256, 4) void first_spike_kernel(
    const float* __restrict__ in, float* __restrict__ out, int batch, int T) {
  const int lane = threadIdx.x & 63;
  const int wave = threadIdx.x >> 6;
  const int row  = blockIdx.x * 4 + wave;
  if (row >= batch) return;  // wave-uniform

  const float4* __restrict__ in4  = (const float4*)(in  + (size_t)row * T);
  nfloat4*      __restrict__ out4 = (nfloat4*)     (out + (size_t)row * T);
  const int chunks = T >> 9;  // 512 elems per iter: 64 lanes * 8 floats

  int first_idx = INT_MAX;
  for (int c = 0; c < chunks; ++c) {
    float4 v0 = in4[(c << 7) + lane];        // elems [c*512 + lane*4, +4)
    float4 v1 = in4[(c << 7) + 64 + lane];   // elems [c*512 + 256 + lane*4, +4)
    const int b0 = (c << 9) + (lane << 2);
    const int b1 = b0 + 256;
    int local = INT_MAX;
    // assign high->low so the lowest index wins within the lane
    if (v1.w != 0.0f) local = b1 + 3;
    if (v1.z != 0.0f) local = b1 + 2;
    if (v1.y != 0.0f) local = b1 + 1;
    if (v1.x != 0.0f) local = b1 + 0;
    if (v0.w != 0.0f) local = b0 + 3;
    if (v0.z != 0.0f) local = b0 + 2;
    if (v0.y != 0.0f) local = b0 + 1;
    if (v0.x != 0.0f) local = b0 + 0;
    if (__ballot(local != INT_MAX)) {  // wave-uniform early exit
      int m = local;
#pragma unroll
      for (int off = 1; off < 64; off <<= 1)
        m = min(m, __shfl_xor(m, off, 64));
      first_idx = m;  // chunks scanned in order -> global first index
      break;
    }
  }

#pragma unroll
  for (int c = 0; c < chunks; ++c) {
    const int b0 = (c << 9) + (lane << 2);
    const int b1 = b0 + 256;
    nfloat4 o0, o1;
    o0.x = (b0 + 0 == first_idx) ? 1.0f : 0.0f;
    o0.y = (b0 + 1 == first_idx) ? 1.0f : 0.0f;
    o0.z = (b0 + 2 == first_idx) ? 1.0f : 0.0f;
    o0.w = (b0 + 3 == first_idx) ? 1.0f : 0.0f;
    o1.x = (b1 + 0 == first_idx) ? 1.0f : 0.0f;
    o1.y = (b1 + 1 == first_idx) ? 1.0f : 0.0f;
    o1.z = (b1 + 2 == first_idx) ? 1.0f : 0.0f;
    o1.w = (b1 + 3 == first_idx) ? 1.0f : 0.0f;
    __builtin_nontemporal_store(o0, &out4[(c << 7) + lane]);
    __builtin_nontemporal_store(o1, &out4[(c << 7) + 64 + lane]);
  }
}

extern "C" void kernel_launch(void* const* d_in, const int* in_sizes, int n_in,
                              void* d_out, int out_size, void* d_ws, size_t ws_size,
                              hipStream_t stream) {
  const float* in = (const float*)d_in[0];
  float* out = (float*)d_out;
  const int T = 2048;                 // time axis per reference setup_inputs
  const int batch = in_sizes[0] / T;  // 16384
  const int waves_per_block = 4;      // 256 threads = 4 wave64, one row each
  dim3 grid((batch + waves_per_block - 1) / waves_per_block);
  first_spike_kernel<<<grid, 256, 0, stream>>>(in, out, batch, T);
}

// Round 4
// 200.135 us; speedup vs baseline: 1.0496x; 1.0496x over previous
//
#include <hip/hip_runtime.h>

// FirstSpikeDetector: out[b][t] = 1.0 iff t is the first index where
// spike_train[b][t] != 0, else 0.0. (NOT/AND/OR gate cascade over a scan
// collapses to "keep only the first spike per row".)
//
// Decomposition:
//   1. hipMemsetAsync(d_out, 0)  -- the 134 MB zero-fill at memset rate
//      (~6.6 TB/s per the harness's own fill dispatches => ~20 us). This is
//      the irreducible write cost since d_out is re-poisoned every launch.
//   2. first_spike_scatter       -- one wave64 per row; lanes read 64 floats
//      (256 B coalesced), __ballot + __ffsll finds the first spike lane,
//      lane 0 stores a single 1.0f. At ~10% firing rate P(resolve in iter 0)
//      = 1 - 0.9^64 ~= 0.9988, so read traffic ~= 16384 x 256 B ~= 4 MB.

__global__ __launch_bounds__(256, 4) void first_spike_scatter(
    const float* __restrict__ in, float* __restrict__ out, int batch, int T) {
  const int lane = threadIdx.x & 63;
  const int wave = threadIdx.x >> 6;
  const int row  = blockIdx.x * 4 + wave;
  if (row >= batch) return;  // wave-uniform

  const float* __restrict__ rowp = in + (size_t)row * T;
  const int iters = T >> 6;  // 64 elems per iteration

  for (int it = 0; it < iters; ++it) {
    float v = rowp[(it << 6) + lane];
    unsigned long long mask = __ballot(v != 0.0f);
    if (mask) {  // wave-uniform
      if (lane == 0) {
        int idx = (it << 6) + (__ffsll(mask) - 1);  // first set lane = first spike
        out[(size_t)row * T + idx] = 1.0f;
      }
      return;
    }
  }
  // no spike in this row: all zeros, nothing to store
}

extern "C" void kernel_launch(void* const* d_in, const int* in_sizes, int n_in,
                              void* d_out, int out_size, void* d_ws, size_t ws_size,
                              hipStream_t stream) {
  const float* in = (const float*)d_in[0];
  float* out = (float*)d_out;
  const int T = 2048;                 // time axis per reference setup_inputs
  const int batch = in_sizes[0] / T;  // 16384

  // Zero the whole output at memset rate (capture-safe: becomes a memset node).
  hipMemsetAsync(d_out, 0, (size_t)out_size * sizeof(float), stream);

  const int waves_per_block = 4;  // 256 threads = 4 wave64, one row each
  dim3 grid((batch + waves_per_block - 1) / waves_per_block);
  first_spike_scatter<<<grid, 256, 0, stream>>>(in, out, batch, T);
}